// Round 1
// baseline (29704.819 us; speedup 1.0000x reference)
//
#include <hip/hip_runtime.h>

// PQMatcher: 256-step scan, B=32, H=1024, IN=512.
// Round-0 design: multi-kernel graph (kernel-boundary sync), fp32 everywhere.
//  - k_init: fold Wp (self-concat) -> Wpf[1024][512]; fold used half of Wg
//            -> Wg2f[1024][1024]; copy v0 into vbuf0.
//  - k_wuq:  WUq[q][b][h] = uq @ Wqf.T  (loop-invariant, hoisted).
//  - per step p: k_A (GRU finish of step p-1, then t = WUp_p + v@Wv.T and
//                gh = v@W_hh.T + b_hh), k_B (s = sum_h tanh(t+WUq)*Vvec),
//                k_C (softmax + c -> rhalf=[up_p|c]), k_D (c_ = sig(rhalf@Wg2f.T)*c),
//                k_E (gi = c_@W_ih.T + b_ih).
//  - k_fin: GRU for the last step -> out[255].
// v and gh are double-buffered (k_A both reads step p-1's and writes step p's).
// GEMVs register-block 8 batch rows/thread so each weight element is loaded
// once per 8 b (keeps per-XCD weight slices ~2-4MB, L2-resident across steps).

#define NB 32
#define H 1024
#define H3 3072
#define LQn 256
#define LPn 256

__device__ __forceinline__ float fsig(float x) { return 1.0f / (1.0f + __expf(-x)); }
__device__ __forceinline__ float ftanh(float x) { return 1.0f - 2.0f / (1.0f + __expf(2.0f * x)); }

// ---------------- init: folds + v0 copy ----------------
__global__ __launch_bounds__(256) void k_init(
    const float* __restrict__ v0, const float* __restrict__ Wp,
    const float* __restrict__ Wg, float* __restrict__ vbuf0,
    float* __restrict__ Wpf, float* __restrict__ Wg2f) {
  int i = blockIdx.x * 256 + threadIdx.x;
  if (i < NB * H) vbuf0[i] = v0[i];
  if (i < 1024 * 512) {
    int n = i >> 9, k = i & 511;
    Wpf[i] = Wp[(size_t)n * 1024 + k] + Wp[(size_t)n * 1024 + k + 512];
  }
  if (i < 1024 * 1024) {
    int j = i >> 10, kk = i & 1023;
    const float* wr = Wg + (size_t)(1024 + j) * 2048;
    // r = [up, up, c, c]: fold duplicated K-halves
    Wg2f[i] = (kk < 512) ? (wr[kk] + wr[kk + 512]) : (wr[kk + 512] + wr[kk + 1024]);
  }
}

// ---------------- WUq = uq @ Wqf.T : [8192,512] x [512,1024] ----------------
__global__ __launch_bounds__(256) void k_wuq(
    const float* __restrict__ A, const float* __restrict__ Wq, float* __restrict__ C) {
  __shared__ float As[16][65];
  __shared__ float Bs[16][65];
  int bm = blockIdx.x * 64, bn = blockIdx.y * 64;
  int t = threadIdx.x;
  int tx = t & 15, ty = t >> 4;
  float acc[4][4] = {};
  for (int k0 = 0; k0 < 512; k0 += 16) {
#pragma unroll
    for (int l = 0; l < 4; ++l) {
      int idx = t + l * 256;
      int row = idx >> 4, kk = idx & 15;
      As[kk][row] = A[(size_t)(bm + row) * 512 + k0 + kk];
      Bs[kk][row] = Wq[(size_t)(bn + row) * 1024 + k0 + kk] +
                    Wq[(size_t)(bn + row) * 1024 + k0 + kk + 512];
    }
    __syncthreads();
#pragma unroll
    for (int kk = 0; kk < 16; ++kk) {
      float a0[4], b0[4];
#pragma unroll
      for (int i = 0; i < 4; ++i) a0[i] = As[kk][ty * 4 + i];
#pragma unroll
      for (int j = 0; j < 4; ++j) b0[j] = Bs[kk][tx * 4 + j];
#pragma unroll
      for (int i = 0; i < 4; ++i)
#pragma unroll
        for (int j = 0; j < 4; ++j) acc[i][j] += a0[i] * b0[j];
    }
    __syncthreads();
  }
#pragma unroll
  for (int i = 0; i < 4; ++i)
#pragma unroll
    for (int j = 0; j < 4; ++j)
      C[(size_t)(bm + ty * 4 + i) * 1024 + bn + tx * 4 + j] = acc[i][j];
}

// ---------------- phase A: GRU finish + t/gh GEMV ----------------
// grid 256 = (slice s=blk&63) x (b-group bg=blk>>6, 8 b each); 256 threads.
__global__ __launch_bounds__(256, 1) void k_A(
    const float* __restrict__ gi, const float* __restrict__ gh_old,
    const float* __restrict__ v_old, const float* __restrict__ up,
    const float* __restrict__ Wv, const float* __restrict__ W_hh,
    const float* __restrict__ b_hh, const float* __restrict__ Wpf,
    float* __restrict__ v_new_g, float* __restrict__ out,
    float* __restrict__ t_out, float* __restrict__ gh_new, int p) {
  int s = blockIdx.x & 63, bg = blockIdx.x >> 6;
  int b0 = bg * 8;
  int tid = threadIdx.x, lane = tid & 63, wave = tid >> 6;
  __shared__ float vnew[8][H];
  __shared__ float upb[8][512];

  if (p == 0) {
    for (int bb = 0; bb < 8; ++bb)
#pragma unroll
      for (int ii = 0; ii < 4; ++ii) {
        int h = tid + ii * 256;
        vnew[bb][h] = v_old[(size_t)(b0 + bb) * H + h];
      }
  } else {
    for (int bb = 0; bb < 8; ++bb) {
      int b = b0 + bb;
      const float* gib = gi + (size_t)b * H3;
      const float* ghb = gh_old + (size_t)b * H3;
#pragma unroll
      for (int ii = 0; ii < 4; ++ii) {
        int h = tid + ii * 256;
        float rg = fsig(gib[h] + ghb[h]);
        float z = fsig(gib[H + h] + ghb[H + h]);
        float nn = ftanh(gib[2 * H + h] + rg * ghb[2 * H + h]);
        float vo = v_old[(size_t)b * H + h];
        float vn = (1.0f - z) * nn + z * vo;
        vnew[bb][h] = vn;
        if (s == 0) {
          v_new_g[(size_t)b * H + h] = vn;
          out[((size_t)(p - 1) * NB + b) * H + h] = vn;
        }
      }
    }
  }
  bool is_t = (s < 16);
  if (is_t) {
    for (int idx = tid; idx < 8 * 512; idx += 256) {
      int bb = idx >> 9, k = idx & 511;
      upb[bb][k] = up[((size_t)p * NB + (b0 + bb)) * 512 + k];
    }
  }
  __syncthreads();

  float vreg[8][16];
#pragma unroll
  for (int bb = 0; bb < 8; ++bb)
#pragma unroll
    for (int i = 0; i < 16; ++i) vreg[bb][i] = vnew[bb][lane + i * 64];

  int n0 = s * 64 + wave * 16;
  for (int rr = 0; rr < 16; ++rr) {
    int n = n0 + rr;
    float acc[8];
#pragma unroll
    for (int bb = 0; bb < 8; ++bb) acc[bb] = 0.0f;
    if (is_t) {
      const float* wr = Wv + (size_t)n * H;
#pragma unroll
      for (int i = 0; i < 16; ++i) {
        float w = wr[lane + i * 64];
#pragma unroll
        for (int bb = 0; bb < 8; ++bb) acc[bb] = fmaf(w, vreg[bb][i], acc[bb]);
      }
      const float* wp = Wpf + (size_t)n * 512;
#pragma unroll
      for (int i = 0; i < 8; ++i) {
        float w = wp[lane + i * 64];
#pragma unroll
        for (int bb = 0; bb < 8; ++bb) acc[bb] = fmaf(w, upb[bb][lane + i * 64], acc[bb]);
      }
#pragma unroll
      for (int bb = 0; bb < 8; ++bb) {
        float a = acc[bb];
#pragma unroll
        for (int o = 32; o >= 1; o >>= 1) a += __shfl_xor(a, o, 64);
        if (lane == 0) t_out[(size_t)(b0 + bb) * H + n] = a;
      }
    } else {
      int m = n - H;
      const float* wr = W_hh + (size_t)m * H;
#pragma unroll
      for (int i = 0; i < 16; ++i) {
        float w = wr[lane + i * 64];
#pragma unroll
        for (int bb = 0; bb < 8; ++bb) acc[bb] = fmaf(w, vreg[bb][i], acc[bb]);
      }
      float bias = b_hh[m];
#pragma unroll
      for (int bb = 0; bb < 8; ++bb) {
        float a = acc[bb];
#pragma unroll
        for (int o = 32; o >= 1; o >>= 1) a += __shfl_xor(a, o, 64);
        if (lane == 0) gh_new[(size_t)(b0 + bb) * H3 + m] = a + bias;
      }
    }
  }
}

// ---------------- phase B: s[b][q] = sum_h tanh(t+WUq)*Vvec ----------------
__global__ __launch_bounds__(64) void k_B(
    const float* __restrict__ t_in, const float* __restrict__ WUq,
    const float* __restrict__ Vvec, float* __restrict__ s_out) {
  int q = blockIdx.x >> 5, b = blockIdx.x & 31;
  int lane = threadIdx.x;
  const float* wq = WUq + ((size_t)q * NB + b) * H;
  const float* tb = t_in + (size_t)b * H;
  const float* vv = Vvec + (size_t)b * H;
  float a = 0.0f;
#pragma unroll
  for (int i = 0; i < 16; ++i) {
    int h = lane + i * 64;
    a += ftanh(tb[h] + wq[h]) * vv[h];
  }
#pragma unroll
  for (int o = 32; o >= 1; o >>= 1) a += __shfl_xor(a, o, 64);
  if (lane == 0) s_out[b * LQn + q] = a;
}

// ---------------- phase C: softmax + c; rhalf[b] = [up_p | c] ----------------
__global__ __launch_bounds__(256) void k_C(
    const float* __restrict__ s_in, const float* __restrict__ uq,
    const float* __restrict__ up, float* __restrict__ rhalf, int p) {
  int b = blockIdx.x;
  int tid = threadIdx.x, lane = tid & 63, wave = tid >> 6;
  __shared__ float a_s[256];
  __shared__ float red[4];
  float sv = s_in[b * LQn + tid];
  float m = sv;
#pragma unroll
  for (int o = 32; o >= 1; o >>= 1) m = fmaxf(m, __shfl_xor(m, o, 64));
  if (lane == 0) red[wave] = m;
  __syncthreads();
  float bm = fmaxf(fmaxf(red[0], red[1]), fmaxf(red[2], red[3]));
  __syncthreads();
  float e = __expf(sv - bm);
  float se = e;
#pragma unroll
  for (int o = 32; o >= 1; o >>= 1) se += __shfl_xor(se, o, 64);
  if (lane == 0) red[wave] = se;
  __syncthreads();
  float tot = red[0] + red[1] + red[2] + red[3];
  a_s[tid] = e / tot;
  __syncthreads();
  // up half
  rhalf[(size_t)b * 1024 + tid] = up[((size_t)p * NB + b) * 512 + tid];
  rhalf[(size_t)b * 1024 + tid + 256] = up[((size_t)p * NB + b) * 512 + tid + 256];
  // c half: c[i] = sum_q a[q] * uq[q][b][i]
  float acc0 = 0.0f, acc1 = 0.0f;
  for (int q = 0; q < LQn; ++q) {
    float a = a_s[q];
    const float* uqr = uq + ((size_t)q * NB + b) * 512;
    acc0 += a * uqr[tid];
    acc1 += a * uqr[tid + 256];
  }
  rhalf[(size_t)b * 1024 + 512 + tid] = acc0;
  rhalf[(size_t)b * 1024 + 512 + tid + 256] = acc1;
}

// ---------------- phase D: c_[b][j] = sig(rhalf@Wg2f.T) * c[j%512] ----------------
__global__ __launch_bounds__(256, 1) void k_D(
    const float* __restrict__ rhalf, const float* __restrict__ Wg2f,
    float* __restrict__ c_g) {
  int s = blockIdx.x & 63, bg = blockIdx.x >> 6, b0 = bg * 8;
  int tid = threadIdx.x, lane = tid & 63, wave = tid >> 6;
  float rreg[8][16];
#pragma unroll
  for (int bb = 0; bb < 8; ++bb)
#pragma unroll
    for (int i = 0; i < 16; ++i)
      rreg[bb][i] = rhalf[(size_t)(b0 + bb) * 1024 + lane + i * 64];
  int j0 = s * 16 + wave * 4;
  for (int rr = 0; rr < 4; ++rr) {
    int j = j0 + rr;
    const float* wr = Wg2f + (size_t)j * 1024;
    float acc[8];
#pragma unroll
    for (int bb = 0; bb < 8; ++bb) acc[bb] = 0.0f;
#pragma unroll
    for (int i = 0; i < 16; ++i) {
      float w = wr[lane + i * 64];
#pragma unroll
      for (int bb = 0; bb < 8; ++bb) acc[bb] = fmaf(w, rreg[bb][i], acc[bb]);
    }
#pragma unroll
    for (int bb = 0; bb < 8; ++bb) {
      float a = acc[bb];
#pragma unroll
      for (int o = 32; o >= 1; o >>= 1) a += __shfl_xor(a, o, 64);
      if (lane == 0) {
        float cv = rhalf[(size_t)(b0 + bb) * 1024 + 512 + (j & 511)];
        c_g[(size_t)(b0 + bb) * 1024 + j] = fsig(a) * cv;
      }
    }
  }
}

// ---------------- phase E: gi = c_ @ W_ih.T + b_ih ----------------
__global__ __launch_bounds__(256, 1) void k_E(
    const float* __restrict__ c_g, const float* __restrict__ W_ih,
    const float* __restrict__ b_ih, float* __restrict__ gi) {
  int s = blockIdx.x & 63, bg = blockIdx.x >> 6, b0 = bg * 8;
  int tid = threadIdx.x, lane = tid & 63, wave = tid >> 6;
  float creg[8][16];
#pragma unroll
  for (int bb = 0; bb < 8; ++bb)
#pragma unroll
    for (int i = 0; i < 16; ++i)
      creg[bb][i] = c_g[(size_t)(b0 + bb) * 1024 + lane + i * 64];
  int r0 = s * 48 + wave * 12;
  for (int rr = 0; rr < 12; ++rr) {
    int r = r0 + rr;
    const float* wr = W_ih + (size_t)r * 1024;
    float acc[8];
#pragma unroll
    for (int bb = 0; bb < 8; ++bb) acc[bb] = 0.0f;
#pragma unroll
    for (int i = 0; i < 16; ++i) {
      float w = wr[lane + i * 64];
#pragma unroll
      for (int bb = 0; bb < 8; ++bb) acc[bb] = fmaf(w, creg[bb][i], acc[bb]);
    }
    float bias = b_ih[r];
#pragma unroll
    for (int bb = 0; bb < 8; ++bb) {
      float a = acc[bb];
#pragma unroll
      for (int o = 32; o >= 1; o >>= 1) a += __shfl_xor(a, o, 64);
      if (lane == 0) gi[(size_t)(b0 + bb) * H3 + r] = a + bias;
    }
  }
}

// ---------------- final GRU for step 255 ----------------
__global__ __launch_bounds__(256) void k_fin(
    const float* __restrict__ gi, const float* __restrict__ gh_old,
    const float* __restrict__ v_old, float* __restrict__ out) {
  int i = blockIdx.x * 256 + threadIdx.x;  // 0..32767
  int b = i >> 10, h = i & 1023;
  const float* gib = gi + (size_t)b * H3;
  const float* ghb = gh_old + (size_t)b * H3;
  float rg = fsig(gib[h] + ghb[h]);
  float z = fsig(gib[H + h] + ghb[H + h]);
  float nn = ftanh(gib[2 * H + h] + rg * ghb[2 * H + h]);
  float vn = (1.0f - z) * nn + z * v_old[i];
  out[(size_t)255 * NB * H + i] = vn;
}

extern "C" void kernel_launch(void* const* d_in, const int* in_sizes, int n_in,
                              void* d_out, int out_size, void* d_ws, size_t ws_size,
                              hipStream_t stream) {
  const float* up = (const float*)d_in[0];
  const float* uq = (const float*)d_in[1];
  const float* v0 = (const float*)d_in[2];
  const float* Vvec = (const float*)d_in[3];
  const float* Wp = (const float*)d_in[4];
  const float* Wq = (const float*)d_in[5];
  const float* Wv = (const float*)d_in[6];
  const float* Wg = (const float*)d_in[7];
  const float* W_ih = (const float*)d_in[8];
  const float* W_hh = (const float*)d_in[9];
  const float* b_ih = (const float*)d_in[10];
  const float* b_hh = (const float*)d_in[11];
  float* out = (float*)d_out;
  float* ws = (float*)d_ws;

  float* vbuf0 = ws;                  // 32768
  float* vbuf1 = ws + 32768;          // 32768
  float* tbuf  = ws + 65536;          // 32768
  float* gh0   = ws + 98304;          // 98304
  float* gh1   = ws + 196608;         // 98304
  float* sbuf  = ws + 294912;         // 8192
  float* rhalf = ws + 303104;         // 32768
  float* cbuf  = ws + 335872;         // 32768
  float* gibuf = ws + 368640;         // 98304
  float* Wpf   = ws + 466944;         // 524288
  float* Wg2f  = ws + 991232;         // 1048576
  float* WUq   = ws + 2039808;        // 8388608  (end: 10428416 floats = 41.7MB)

  k_init<<<4096, 256, 0, stream>>>(v0, Wp, Wg, vbuf0, Wpf, Wg2f);
  k_wuq<<<dim3(128, 16), 256, 0, stream>>>(uq, Wq, WUq);

  for (int p = 0; p < 256; ++p) {
    float* ghn = (p & 1) ? gh1 : gh0;
    float* gho = (p & 1) ? gh0 : gh1;
    float* vn = (p & 1) ? vbuf1 : vbuf0;
    float* vo = (p & 1) ? vbuf0 : vbuf1;
    if (p == 0) { vo = vbuf0; vn = vbuf1; }  // p=0 reads vbuf0 (v0), writes nothing
    k_A<<<256, 256, 0, stream>>>(gibuf, gho, vo, up, Wv, W_hh, b_hh, Wpf,
                                 vn, out, tbuf, ghn, p);
    k_B<<<8192, 64, 0, stream>>>(tbuf, WUq, Vvec, sbuf);
    k_C<<<32, 256, 0, stream>>>(sbuf, uq, up, rhalf, p);
    k_D<<<256, 256, 0, stream>>>(rhalf, Wg2f, cbuf);
    k_E<<<256, 256, 0, stream>>>(cbuf, W_ih, b_ih, gibuf);
  }
  k_fin<<<128, 256, 0, stream>>>(gibuf, gh1, vbuf1, out);
}